// Round 8
// baseline (388.895 us; speedup 1.0000x reference)
//
#include <hip/hip_runtime.h>
#include <hip/hip_bf16.h>

#define D_MODEL 512
#define N_HEADS 8
#define D_HEAD  64
#define SEQ     2048
#define BATCH   4
#define ROWS    (BATCH * SEQ)   /* 8192 */
#define EPS     1e-5f
#define SCALE   0.125f          /* 1/sqrt(64), exact pow2 -> folded into q epilogue */

typedef __attribute__((ext_vector_type(8))) short short8;   // 8 bf16 (4 VGPRs)
typedef __attribute__((ext_vector_type(4))) float f32x4;    // MFMA C/D

__device__ __forceinline__ unsigned short f2bf(float f) {
  return __builtin_bit_cast(unsigned short, __float2bfloat16(f));  // RNE
}

// ---------------------------------------------------------------------------
// Kernel 0: one-time W transpose+convert: fp32 [K][N] -> bf16 Wt[N][K].
// grid (8 bk, 8 bn, 4 mat). Same work every call (graph-capture safe).
// ---------------------------------------------------------------------------
__global__ __launch_bounds__(256) void wtrans_kernel(const float* __restrict__ wq,
                                                     const float* __restrict__ wk,
                                                     const float* __restrict__ wv,
                                                     const float* __restrict__ wo,
                                                     unsigned short* __restrict__ wt) {
  __shared__ float T[64][68];
  const float* src;
  switch (blockIdx.z) { case 0: src = wq; break; case 1: src = wk; break;
                        case 2: src = wv; break; default: src = wo; }
  const int tid = threadIdx.x;
  const int bk = blockIdx.x, bn = blockIdx.y;
  {
    const int k = tid >> 2, n0 = (tid & 3) * 16;
#pragma unroll
    for (int j = 0; j < 4; j++) {
      const float4 f = *(const float4*)(src + (size_t)(bk * 64 + k) * D_MODEL + bn * 64 + n0 + j * 4);
      *(float4*)&T[k][n0 + j * 4] = f;
    }
  }
  __syncthreads();
  {
    const int n = tid >> 2, k0 = (tid & 3) * 16;
    short8 t0, t1;
#pragma unroll
    for (int j = 0; j < 8; j++) t0[j] = (short)f2bf(T[k0 + j][n]);
#pragma unroll
    for (int j = 0; j < 8; j++) t1[j] = (short)f2bf(T[k0 + 8 + j][n]);
    unsigned short* dst = wt + (size_t)blockIdx.z * D_MODEL * D_MODEL
                             + (size_t)(bn * 64 + n) * D_MODEL + bk * 64 + k0;
    *(short8*)dst = t0;
    *(short8*)(dst + 8) = t1;
  }
}

// ---------------------------------------------------------------------------
// Kernel 1: LayerNorm. fp32 math (known-good), bf16 output.
// ---------------------------------------------------------------------------
__global__ __launch_bounds__(128) void ln_kernel(const float* __restrict__ x,
                                                 const float* __restrict__ gamma,
                                                 const float* __restrict__ beta,
                                                 unsigned short* __restrict__ xn) {
  const int row = blockIdx.x;
  const int t   = threadIdx.x;
  const float4 v = ((const float4*)(x + (size_t)row * D_MODEL))[t];
  float s  = v.x + v.y + v.z + v.w;
  float s2 = v.x*v.x + v.y*v.y + v.z*v.z + v.w*v.w;
#pragma unroll
  for (int o = 32; o > 0; o >>= 1) {
    s  += __shfl_down(s,  o, 64);
    s2 += __shfl_down(s2, o, 64);
  }
  __shared__ float ps[2], ps2[2];
  if ((t & 63) == 0) { ps[t >> 6] = s; ps2[t >> 6] = s2; }
  __syncthreads();
  s  = ps[0] + ps[1];
  s2 = ps2[0] + ps2[1];
  const float mu  = s * (1.0f / D_MODEL);
  const float var = s2 * (1.0f / D_MODEL) - mu * mu;
  const float rs  = rsqrtf(var + EPS);
  const float4 g = ((const float4*)gamma)[t];
  const float4 b = ((const float4*)beta)[t];
  ushort4 o;
  o.x = f2bf((v.x - mu) * rs * g.x + b.x);
  o.y = f2bf((v.y - mu) * rs * g.y + b.y);
  o.z = f2bf((v.z - mu) * rs * g.z + b.z);
  o.w = f2bf((v.w - mu) * rs * g.w + b.w);
  ((ushort4*)(xn + (size_t)row * D_MODEL))[t] = o;
}

// ---------------------------------------------------------------------------
// Shared bf16-MFMA GEMM mainloop, LDS-free: C[64x64] = A[64x512]*Wt^T slice.
// A bf16 row-major; Wt bf16 [N][K] (n-major, pre-transposed). B-frags load
// 16B straight from global (L2-resident, 512KB/matrix). No barriers.
// A-frag: lane(l4,lg) holds A[row=wv*16+l4][kt*32+lg*8+j]; B-frag:
// Wt[n=bn*64+nt*16+l4][kt*32+lg*8+j] -- audited gemm_bt operand form.
// ---------------------------------------------------------------------------
__device__ __forceinline__ void bf16_gemm_global(const unsigned short* __restrict__ A,
                                                 const unsigned short* __restrict__ Wt,
                                                 f32x4 (&acc)[4], int bm, int bn) {
  const int tid = threadIdx.x, lane = tid & 63;
  const int l4 = lane & 15, lg = lane >> 4, wv_ = tid >> 6;
  short8 af[16];
  const unsigned short* ap = A + (size_t)(bm * 64 + wv_ * 16 + l4) * D_MODEL + lg * 8;
#pragma unroll
  for (int kt = 0; kt < 16; kt++) af[kt] = *(const short8*)(ap + kt * 32);
  const unsigned short* bp = Wt + (size_t)(bn * 64 + l4) * D_MODEL + lg * 8;
#pragma unroll
  for (int kt = 0; kt < 16; kt++) {
#pragma unroll
    for (int nt = 0; nt < 4; nt++) {
      const short8 b = *(const short8*)(bp + (size_t)nt * 16 * D_MODEL + kt * 32);
      acc[nt] = __builtin_amdgcn_mfma_f32_16x16x32_bf16(af[kt], b, acc[nt], 0, 0, 0);
    }
  }
}

// ---------------------------------------------------------------------------
// Kernel 2: QKV projection. grid = (ROWS/64, N_HEADS, 3). No LDS.
// q output pre-scaled by 1/8 (exact pow2).
// ---------------------------------------------------------------------------
__global__ __launch_bounds__(256) void qkv_mfma_kernel(const unsigned short* __restrict__ xn,
                                                       const unsigned short* __restrict__ wt,
                                                       const float* __restrict__ bq,
                                                       const float* __restrict__ bk_,
                                                       const float* __restrict__ bv_,
                                                       unsigned short* __restrict__ qo,
                                                       unsigned short* __restrict__ ko,
                                                       unsigned short* __restrict__ vo) {
  const int z = blockIdx.z;
  const unsigned short* W = wt + (size_t)z * D_MODEL * D_MODEL;
  const float* bias = (z == 0) ? bq : ((z == 1) ? bk_ : bv_);
  unsigned short* out = (z == 0) ? qo : ((z == 1) ? ko : vo);
  const float scale = (z == 0) ? SCALE : 1.0f;

  f32x4 acc[4];
#pragma unroll
  for (int i = 0; i < 4; i++) acc[i] = (f32x4){0.f, 0.f, 0.f, 0.f};
  bf16_gemm_global(xn, W, acc, blockIdx.x, blockIdx.y);

  const int lane = threadIdx.x & 63, wv_ = threadIdx.x >> 6;
  const int l4 = lane & 15, lg = lane >> 4;
  const int h = blockIdx.y;
#pragma unroll
  for (int nt = 0; nt < 4; nt++) {
    const float bb = bias[h * 64 + nt * 16 + l4];
#pragma unroll
    for (int r = 0; r < 4; r++) {
      const int row = blockIdx.x * 64 + wv_ * 16 + lg * 4 + r;
      const int b_  = row >> 11;          // row / SEQ
      const int s   = row & (SEQ - 1);    // row % SEQ
      out[((size_t)(b_ * N_HEADS + h) * SEQ + s) * D_HEAD + nt * 16 + l4] =
          f2bf((acc[nt][r] + bb) * scale);
    }
  }
}

// ---------------------------------------------------------------------------
// Kernel 3: MFMA flash attention, KVBLK=64.
//   K: register-prefetched B-frags straight from global/L2 (no K LDS).
//   V: register-prefetched, transposed into LDS Vt[64][72] per tile.
//   2 barriers per 64-kv tile (was per 32); setprio(1) around MFMA clusters.
// ---------------------------------------------------------------------------
__global__ __launch_bounds__(256) void attn_mfma_kernel(const unsigned short* __restrict__ q,
                                                        const unsigned short* __restrict__ k,
                                                        const unsigned short* __restrict__ v,
                                                        unsigned short* __restrict__ att) {
  __shared__ __align__(16) unsigned short Vt_lds[64 * 72];   // V^T [d][j], pad->72
  __shared__ __align__(16) unsigned short P_lds[4][16 * 72]; // per wave [q][j]

  const int tid  = threadIdx.x;
  const int lane = tid & 63;
  const int w    = tid >> 6;
  const int l4   = lane & 15;     // C/D col | A row | B row
  const int lg   = lane >> 4;     // k-slice group

  // XCD-chunked swizzle: each XCD's 128 blocks = 4 complete heads -> K/V L2-resident.
  const int swz = (blockIdx.x & 7) * 128 + (blockIdx.x >> 3);
  const int qb  = swz & 31;       // q-block (64 rows)
  const int bh  = swz >> 5;       // batch*head

  const unsigned short* qbase = q + (size_t)bh * SEQ * D_HEAD;
  const unsigned short* kbase = k + (size_t)bh * SEQ * D_HEAD;
  const unsigned short* vbase = v + (size_t)bh * SEQ * D_HEAD;

  // Q A-frags (pre-scaled upstream): lane holds Q[row=l4][d=dt*32+lg*8+..]
  short8 aq[2];
  {
    const unsigned short* qp = qbase + (size_t)(qb * 64 + w * 16 + l4) * D_HEAD + lg * 8;
    aq[0] = *(const short8*)(qp);
    aq[1] = *(const short8*)(qp + 32);
  }

  f32x4 o[4];
#pragma unroll
  for (int i = 0; i < 4; i++) o[i] = (f32x4){0.f, 0.f, 0.f, 0.f};
  float m_[4] = {-1e30f, -1e30f, -1e30f, -1e30f};
  float l_[4] = {0.f, 0.f, 0.f, 0.f};

  // V staging roles: thread stages V[j=vj][d = vd0..vd0+15]
  const int vj  = tid & 63;
  const int vd0 = (tid >> 6) * 16;

  // register prefetch buffers (tile 0)
  short8 kf[8];   // [kt2*2+dt] = K[kv0+kt2*16+l4][dt*32+lg*8+..]
  short8 vf[2];
#pragma unroll
  for (int kt2 = 0; kt2 < 4; kt2++)
#pragma unroll
    for (int dt = 0; dt < 2; dt++)
      kf[kt2 * 2 + dt] = *(const short8*)(kbase + (size_t)(kt2 * 16 + l4) * D_HEAD + dt * 32 + lg * 8);
  vf[0] = *(const short8*)(vbase + (size_t)vj * D_HEAD + vd0);
  vf[1] = *(const short8*)(vbase + (size_t)vj * D_HEAD + vd0 + 8);

  for (int t = 0; t < SEQ / 64; t++) {
    __syncthreads();   // Vt of previous tile fully consumed
    {  // write V^T tile from prefetched regs (free: 2 lanes/bank merge)
#pragma unroll
      for (int i = 0; i < 2; i++)
#pragma unroll
        for (int e = 0; e < 8; e++)
          Vt_lds[(vd0 + i * 8 + e) * 72 + vj] = (unsigned short)vf[i][e];
    }
    __syncthreads();

    // QK^T: four 16(q) x 16(k) tiles from register K-frags
    f32x4 s[4];
    __builtin_amdgcn_s_setprio(1);
#pragma unroll
    for (int kt2 = 0; kt2 < 4; kt2++) {
      f32x4 acc = (f32x4){0.f, 0.f, 0.f, 0.f};
      acc = __builtin_amdgcn_mfma_f32_16x16x32_bf16(aq[0], kf[kt2 * 2 + 0], acc, 0, 0, 0);
      acc = __builtin_amdgcn_mfma_f32_16x16x32_bf16(aq[1], kf[kt2 * 2 + 1], acc, 0, 0, 0);
      s[kt2] = acc;
    }
    __builtin_amdgcn_s_setprio(0);

    // prefetch K/V for next tile (latency hides under softmax+PV+barrier)
    if (t < SEQ / 64 - 1) {
      const int kv0n = (t + 1) * 64;
#pragma unroll
      for (int kt2 = 0; kt2 < 4; kt2++)
#pragma unroll
        for (int dt = 0; dt < 2; dt++)
          kf[kt2 * 2 + dt] = *(const short8*)(kbase + (size_t)(kv0n + kt2 * 16 + l4) * D_HEAD + dt * 32 + lg * 8);
      vf[0] = *(const short8*)(vbase + (size_t)(kv0n + vj) * D_HEAD + vd0);
      vf[1] = *(const short8*)(vbase + (size_t)(kv0n + vj) * D_HEAD + vd0 + 8);
    }

    // online softmax. Lane holds rows q=lg*4+r, col j=kt2*16+l4.
#pragma unroll
    for (int r = 0; r < 4; r++) {
      float mt = fmaxf(fmaxf(s[0][r], s[1][r]), fmaxf(s[2][r], s[3][r]));
#pragma unroll
      for (int mask = 1; mask <= 8; mask <<= 1)
        mt = fmaxf(mt, __shfl_xor(mt, mask, 64));
      const float mn   = fmaxf(m_[r], mt);
      const float corr = __expf(m_[r] - mn);
      float p[4];
      float rs = 0.f;
#pragma unroll
      for (int kt2 = 0; kt2 < 4; kt2++) { p[kt2] = __expf(s[kt2][r] - mn); rs += p[kt2]; }
#pragma unroll
      for (int mask = 1; mask <= 8; mask <<= 1)
        rs += __shfl_xor(rs, mask, 64);
      l_[r] = l_[r] * corr + rs;
      m_[r] = mn;
      o[0][r] *= corr; o[1][r] *= corr; o[2][r] *= corr; o[3][r] *= corr;
      const int qr = lg * 4 + r;
#pragma unroll
      for (int kt2 = 0; kt2 < 4; kt2++)
        P_lds[w][qr * 72 + kt2 * 16 + l4] = f2bf(p[kt2]);
    }
    // same-wave LDS write->read: lockstep wave + drained lgkm is sufficient
    asm volatile("s_waitcnt lgkmcnt(0)" ::: "memory");
    __builtin_amdgcn_sched_barrier(0);

    // PV: O[q][d] += P(16x64) * V(64x64); contraction split j=0..31 / 32..63
    const short8 pa0 = *(const short8*)&P_lds[w][l4 * 72 + lg * 8];
    const short8 pa1 = *(const short8*)&P_lds[w][l4 * 72 + 32 + lg * 8];
    __builtin_amdgcn_s_setprio(1);
#pragma unroll
    for (int dtile = 0; dtile < 4; dtile++) {
      const short8 bv0 = *(const short8*)&Vt_lds[(dtile * 16 + l4) * 72 + lg * 8];
      const short8 bv1 = *(const short8*)&Vt_lds[(dtile * 16 + l4) * 72 + 32 + lg * 8];
      o[dtile] = __builtin_amdgcn_mfma_f32_16x16x32_bf16(pa0, bv0, o[dtile], 0, 0, 0);
      o[dtile] = __builtin_amdgcn_mfma_f32_16x16x32_bf16(pa1, bv1, o[dtile], 0, 0, 0);
    }
    __builtin_amdgcn_s_setprio(0);
  }

  // epilogue: divide by l, write bf16 att[b][s][h*64+d]
  const int b_ = bh >> 3, h = bh & 7;
#pragma unroll
  for (int r = 0; r < 4; r++) {
    const int qrow = qb * 64 + w * 16 + lg * 4 + r;
    const float inv = 1.0f / l_[r];
    unsigned short* op = att + ((size_t)(b_ * SEQ + qrow)) * D_MODEL + h * D_HEAD;
#pragma unroll
    for (int dtile = 0; dtile < 4; dtile++)
      op[dtile * 16 + l4] = f2bf(o[dtile][r] * inv);
  }
}

// ---------------------------------------------------------------------------
// Kernel 4: output projection + bias + residual. grid = (ROWS/64, 8). No LDS.
// ---------------------------------------------------------------------------
__global__ __launch_bounds__(256) void proj_mfma_kernel(const unsigned short* __restrict__ att,
                                                        const unsigned short* __restrict__ wot,
                                                        const float* __restrict__ bo,
                                                        const float* __restrict__ x,
                                                        float* __restrict__ out) {
  f32x4 acc[4];
#pragma unroll
  for (int i = 0; i < 4; i++) acc[i] = (f32x4){0.f, 0.f, 0.f, 0.f};
  bf16_gemm_global(att, wot, acc, blockIdx.x, blockIdx.y);

  const int lane = threadIdx.x & 63, wv_ = threadIdx.x >> 6;
  const int l4 = lane & 15, lg = lane >> 4;
#pragma unroll
  for (int nt = 0; nt < 4; nt++) {
    const float bb = bo[blockIdx.y * 64 + nt * 16 + l4];
#pragma unroll
    for (int r = 0; r < 4; r++) {
      const int row = blockIdx.x * 64 + wv_ * 16 + lg * 4 + r;
      const size_t off = (size_t)row * D_MODEL + blockIdx.y * 64 + nt * 16 + l4;
      out[off] = acc[nt][r] + bb + x[off];
    }
  }
}

// ---------------------------------------------------------------------------
extern "C" void kernel_launch(void* const* d_in, const int* in_sizes, int n_in,
                              void* d_out, int out_size, void* d_ws, size_t ws_size,
                              hipStream_t stream) {
  const float* x     = (const float*)d_in[0];
  const float* wq    = (const float*)d_in[1];
  const float* bq    = (const float*)d_in[2];
  const float* wk    = (const float*)d_in[3];
  const float* bk    = (const float*)d_in[4];
  const float* wv    = (const float*)d_in[5];
  const float* bv    = (const float*)d_in[6];
  const float* wo    = (const float*)d_in[7];
  const float* bo    = (const float*)d_in[8];
  const float* gamma = (const float*)d_in[9];
  const float* beta  = (const float*)d_in[10];
  float* out = (float*)d_out;

  // bf16 workspace: xn | q | k | v (4 x 8 MiB) | wt (4 x 512 KiB); att = xn
  unsigned short* xn  = (unsigned short*)d_ws;
  unsigned short* q   = xn + (size_t)ROWS * D_MODEL;
  unsigned short* k   = q  + (size_t)ROWS * D_MODEL;
  unsigned short* v   = k  + (size_t)ROWS * D_MODEL;
  unsigned short* wt  = v  + (size_t)ROWS * D_MODEL;   // [4][512][512] n-major
  unsigned short* att = xn;  // xn dead after qkv

  wtrans_kernel<<<dim3(8, 8, 4), 256, 0, stream>>>(wq, wk, wv, wo, wt);
  ln_kernel<<<ROWS, 128, 0, stream>>>(x, gamma, beta, xn);
  qkv_mfma_kernel<<<dim3(ROWS / 64, N_HEADS, 3), 256, 0, stream>>>(
      xn, wt, bq, bk, bv, q, k, v);
  attn_mfma_kernel<<<1024, 256, 0, stream>>>(q, k, v, att);
  proj_mfma_kernel<<<dim3(ROWS / 64, D_MODEL / 64), 256, 0, stream>>>(
      att, wt + (size_t)3 * D_MODEL * D_MODEL, bo, x, out);
}

// Round 9
// 374.937 us; speedup vs baseline: 1.0372x; 1.0372x over previous
//
#include <hip/hip_runtime.h>
#include <hip/hip_bf16.h>

#define D_MODEL 512
#define N_HEADS 8
#define D_HEAD  64
#define SEQ     2048
#define BATCH   4
#define ROWS    (BATCH * SEQ)   /* 8192 */
#define EPS     1e-5f
#define SCALE   0.125f          /* 1/sqrt(64), exact pow2 -> folded into q epilogue */

typedef __attribute__((ext_vector_type(8))) short short8;   // 8 bf16 (4 VGPRs)
typedef __attribute__((ext_vector_type(4))) float f32x4;    // MFMA C/D

__device__ __forceinline__ unsigned short f2bf(float f) {
  return __builtin_bit_cast(unsigned short, __float2bfloat16(f));  // RNE
}

// ---------------------------------------------------------------------------
// Kernel 0a: one-time W transpose+convert: fp32 [K][N] -> bf16 Wt[N][K].
// ---------------------------------------------------------------------------
__global__ __launch_bounds__(256) void wtrans_kernel(const float* __restrict__ wq,
                                                     const float* __restrict__ wk,
                                                     const float* __restrict__ wv,
                                                     const float* __restrict__ wo,
                                                     unsigned short* __restrict__ wt) {
  __shared__ float T[64][68];
  const float* src;
  switch (blockIdx.z) { case 0: src = wq; break; case 1: src = wk; break;
                        case 2: src = wv; break; default: src = wo; }
  const int tid = threadIdx.x;
  const int bk = blockIdx.x, bn = blockIdx.y;
  {
    const int k = tid >> 2, n0 = (tid & 3) * 16;
#pragma unroll
    for (int j = 0; j < 4; j++) {
      const float4 f = *(const float4*)(src + (size_t)(bk * 64 + k) * D_MODEL + bn * 64 + n0 + j * 4);
      *(float4*)&T[k][n0 + j * 4] = f;
    }
  }
  __syncthreads();
  {
    const int n = tid >> 2, k0 = (tid & 3) * 16;
    short8 t0, t1;
#pragma unroll
    for (int j = 0; j < 8; j++) t0[j] = (short)f2bf(T[k0 + j][n]);
#pragma unroll
    for (int j = 0; j < 8; j++) t1[j] = (short)f2bf(T[k0 + 8 + j][n]);
    unsigned short* dst = wt + (size_t)blockIdx.z * D_MODEL * D_MODEL
                             + (size_t)(bn * 64 + n) * D_MODEL + bk * 64 + k0;
    *(short8*)dst = t0;
    *(short8*)(dst + 8) = t1;
  }
}

// ---------------------------------------------------------------------------
// Kernel 0b: V transpose (bf16): v[bh][s][64] -> vt[bh][64][SEQ].
// grid (SEQ/64, BATCH*N_HEADS). Enables barrier-free attention PV.
// ---------------------------------------------------------------------------
__global__ __launch_bounds__(256) void vtrans_kernel(const unsigned short* __restrict__ v,
                                                     unsigned short* __restrict__ vt) {
  __shared__ unsigned short T[64 * 72];
  const int tid = threadIdx.x;
  const int sb = blockIdx.x, bh = blockIdx.y;
  const unsigned short* src = v + ((size_t)bh * SEQ + sb * 64) * D_HEAD;
  {
    const int s = tid >> 2, d0 = (tid & 3) * 16;
    const short8 a = *(const short8*)(src + s * D_HEAD + d0);
    const short8 b = *(const short8*)(src + s * D_HEAD + d0 + 8);
    *(short8*)&T[s * 72 + d0] = a;
    *(short8*)&T[s * 72 + d0 + 8] = b;
  }
  __syncthreads();
  {
    const int d = tid >> 2, s0 = (tid & 3) * 16;
    short8 o0, o1;
#pragma unroll
    for (int j = 0; j < 8; j++) o0[j] = (short)T[(s0 + j) * 72 + d];
#pragma unroll
    for (int j = 0; j < 8; j++) o1[j] = (short)T[(s0 + 8 + j) * 72 + d];
    unsigned short* dst = vt + (size_t)bh * D_HEAD * SEQ + (size_t)d * SEQ + sb * 64 + s0;
    *(short8*)dst = o0;
    *(short8*)(dst + 8) = o1;
  }
}

// ---------------------------------------------------------------------------
// Kernel 1: LayerNorm. fp32 math (known-good), bf16 output.
// ---------------------------------------------------------------------------
__global__ __launch_bounds__(128) void ln_kernel(const float* __restrict__ x,
                                                 const float* __restrict__ gamma,
                                                 const float* __restrict__ beta,
                                                 unsigned short* __restrict__ xn) {
  const int row = blockIdx.x;
  const int t   = threadIdx.x;
  const float4 v = ((const float4*)(x + (size_t)row * D_MODEL))[t];
  float s  = v.x + v.y + v.z + v.w;
  float s2 = v.x*v.x + v.y*v.y + v.z*v.z + v.w*v.w;
#pragma unroll
  for (int o = 32; o > 0; o >>= 1) {
    s  += __shfl_down(s,  o, 64);
    s2 += __shfl_down(s2, o, 64);
  }
  __shared__ float ps[2], ps2[2];
  if ((t & 63) == 0) { ps[t >> 6] = s; ps2[t >> 6] = s2; }
  __syncthreads();
  s  = ps[0] + ps[1];
  s2 = ps2[0] + ps2[1];
  const float mu  = s * (1.0f / D_MODEL);
  const float var = s2 * (1.0f / D_MODEL) - mu * mu;
  const float rs  = rsqrtf(var + EPS);
  const float4 g = ((const float4*)gamma)[t];
  const float4 b = ((const float4*)beta)[t];
  ushort4 o;
  o.x = f2bf((v.x - mu) * rs * g.x + b.x);
  o.y = f2bf((v.y - mu) * rs * g.y + b.y);
  o.z = f2bf((v.z - mu) * rs * g.z + b.z);
  o.w = f2bf((v.w - mu) * rs * g.w + b.w);
  ((ushort4*)(xn + (size_t)row * D_MODEL))[t] = o;
}

// ---------------------------------------------------------------------------
// Shared bf16-MFMA GEMM: C[64x64] = A[64x512] * Wt[N][K] slice.
// BK=64, double-buffered LDS Bs[2][64n][64k], XOR-granule swizzle (attn
// K_lds-proven: phys = logical ^ (row&7), involution on both sides).
// Staging: thread t owns row n=t>>2, 32B (2 granules); write conflict-free,
// read conflict-free b128. One barrier per K-step (9 total).
// ---------------------------------------------------------------------------
__device__ __forceinline__ void bf16_gemm_lds(const unsigned short* __restrict__ A,
                                              const unsigned short* __restrict__ Wt,
                                              unsigned short (&Bs)[2][64 * 64],
                                              f32x4 (&acc)[4],
                                              int bm, int bn) {
  const int tid = threadIdx.x, lane = tid & 63;
  const int l4 = lane & 15, lg = lane >> 4, w = tid >> 6;

  // A-frags: lane holds A[row = bm*64 + w*16 + l4][kt8*32 + lg*8 + j]
  short8 af[16];
  const unsigned short* ap = A + (size_t)(bm * 64 + w * 16 + l4) * D_MODEL + lg * 8;
#pragma unroll
  for (int kt8 = 0; kt8 < 16; kt8++) af[kt8] = *(const short8*)(ap + kt8 * 32);

  // staging role: row n = tid>>2, logical granules {2c, 2c+1}, c = tid&3
  const int n = tid >> 2, c = tid & 3;
  const unsigned short* bsrc = Wt + (size_t)(bn * 64 + n) * D_MODEL;
  const int g0 = (2 * c)     ^ (n & 7);   // physical granule (write swizzle)
  const int g1 = (2 * c + 1) ^ (n & 7);

  // prologue: stage kt=0 into buf 0
  short8 r0 = *(const short8*)(bsrc + (2 * c) * 8);
  short8 r1 = *(const short8*)(bsrc + (2 * c + 1) * 8);
  *(short8*)&Bs[0][n * 64 + g0 * 8] = r0;
  *(short8*)&Bs[0][n * 64 + g1 * 8] = r1;
  __syncthreads();

  int cur = 0;
  for (int kt = 0; kt < 8; kt++) {
    // issue next tile's loads early (hide under MFMA)
    if (kt < 7) {
      r0 = *(const short8*)(bsrc + (kt + 1) * 64 + (2 * c) * 8);
      r1 = *(const short8*)(bsrc + (kt + 1) * 64 + (2 * c + 1) * 8);
    }
    // compute current tile: read phys granule (dt*4+lg)^(l4&7) of row nt*16+l4
#pragma unroll
    for (int dt = 0; dt < 2; dt++) {
#pragma unroll
      for (int nt = 0; nt < 4; nt++) {
        const int row = nt * 16 + l4;
        const short8 b = *(const short8*)&Bs[cur][row * 64 + ((dt * 4 + lg) ^ (l4 & 7)) * 8];
        acc[nt] = __builtin_amdgcn_mfma_f32_16x16x32_bf16(af[kt * 2 + dt], b, acc[nt], 0, 0, 0);
      }
    }
    // write next tile late (compiler inserts vmcnt wait)
    if (kt < 7) {
      *(short8*)&Bs[cur ^ 1][n * 64 + g0 * 8] = r0;
      *(short8*)&Bs[cur ^ 1][n * 64 + g1 * 8] = r1;
    }
    __syncthreads();
    cur ^= 1;
  }
}

// ---------------------------------------------------------------------------
// Kernel 2: QKV projection. grid = (ROWS/64, N_HEADS, 3).
// q output pre-scaled by 1/8 (exact pow2).
// ---------------------------------------------------------------------------
__global__ __launch_bounds__(256) void qkv_mfma_kernel(const unsigned short* __restrict__ xn,
                                                       const unsigned short* __restrict__ wt,
                                                       const float* __restrict__ bq,
                                                       const float* __restrict__ bk_,
                                                       const float* __restrict__ bv_,
                                                       unsigned short* __restrict__ qo,
                                                       unsigned short* __restrict__ ko,
                                                       unsigned short* __restrict__ vo) {
  __shared__ __align__(16) unsigned short Bs[2][64 * 64];
  const int z = blockIdx.z;
  const unsigned short* W = wt + (size_t)z * D_MODEL * D_MODEL;
  const float* bias = (z == 0) ? bq : ((z == 1) ? bk_ : bv_);
  unsigned short* out = (z == 0) ? qo : ((z == 1) ? ko : vo);
  const float scale = (z == 0) ? SCALE : 1.0f;

  f32x4 acc[4];
#pragma unroll
  for (int i = 0; i < 4; i++) acc[i] = (f32x4){0.f, 0.f, 0.f, 0.f};
  bf16_gemm_lds(xn, W, Bs, acc, blockIdx.x, blockIdx.y);

  const int lane = threadIdx.x & 63, wv_ = threadIdx.x >> 6;
  const int l4 = lane & 15, lg = lane >> 4;
  const int h = blockIdx.y;
#pragma unroll
  for (int nt = 0; nt < 4; nt++) {
    const float bb = bias[h * 64 + nt * 16 + l4];
#pragma unroll
    for (int r = 0; r < 4; r++) {
      const int row = blockIdx.x * 64 + wv_ * 16 + lg * 4 + r;
      const int b_  = row >> 11;          // row / SEQ
      const int s   = row & (SEQ - 1);    // row % SEQ
      out[((size_t)(b_ * N_HEADS + h) * SEQ + s) * D_HEAD + nt * 16 + l4] =
          f2bf((acc[nt][r] + bb) * scale);
    }
  }
}

// ---------------------------------------------------------------------------
// Kernel 3: MFMA flash attention, BARRIER-FREE. KVBLK=64.
//   K and V^T both register-prefetched straight from global/L2.
//   LDS only for the wave-private P roundtrip (lgkm fence, no barrier).
//   Per-lane partial softmax denominator, reduced once at the end.
// ---------------------------------------------------------------------------
__global__ __launch_bounds__(256) void attn_mfma_kernel(const unsigned short* __restrict__ q,
                                                        const unsigned short* __restrict__ k,
                                                        const unsigned short* __restrict__ vt,
                                                        unsigned short* __restrict__ att) {
  __shared__ __align__(16) unsigned short P_lds[4][16 * 72]; // per wave [q][j]

  const int tid  = threadIdx.x;
  const int lane = tid & 63;
  const int w    = tid >> 6;
  const int l4   = lane & 15;     // C/D col | A row | B row
  const int lg   = lane >> 4;     // k-slice group

  // XCD-chunked swizzle: each XCD's 128 blocks = 4 complete heads.
  const int swz = (blockIdx.x & 7) * 128 + (blockIdx.x >> 3);
  const int qb  = swz & 31;       // q-block (64 rows)
  const int bh  = swz >> 5;       // batch*head

  const unsigned short* qbase  = q  + (size_t)bh * SEQ * D_HEAD;
  const unsigned short* kbase  = k  + (size_t)bh * SEQ * D_HEAD;
  const unsigned short* vtbase = vt + (size_t)bh * D_HEAD * SEQ;  // [d][s]

  // Q A-frags (pre-scaled upstream): lane holds Q[row=l4][d=dt*32+lg*8+..]
  short8 aq[2];
  {
    const unsigned short* qp = qbase + (size_t)(qb * 64 + w * 16 + l4) * D_HEAD + lg * 8;
    aq[0] = *(const short8*)(qp);
    aq[1] = *(const short8*)(qp + 32);
  }

  f32x4 o[4];
#pragma unroll
  for (int i = 0; i < 4; i++) o[i] = (f32x4){0.f, 0.f, 0.f, 0.f};
  float m_[4] = {-1e30f, -1e30f, -1e30f, -1e30f};
  float l_[4] = {0.f, 0.f, 0.f, 0.f};   // per-lane partial sums

  // register prefetch (tile 0)
  short8 kf[8];   // [kt2*2+dt] = K[kt2*16+l4][dt*32+lg*8+..]
  short8 vf[8];   // [dtile*2+hf] = Vt[dtile*16+l4][hf*32+lg*8+..]
#pragma unroll
  for (int kt2 = 0; kt2 < 4; kt2++)
#pragma unroll
    for (int dt = 0; dt < 2; dt++)
      kf[kt2 * 2 + dt] = *(const short8*)(kbase + (size_t)(kt2 * 16 + l4) * D_HEAD + dt * 32 + lg * 8);
#pragma unroll
  for (int dtile = 0; dtile < 4; dtile++)
#pragma unroll
    for (int hf = 0; hf < 2; hf++)
      vf[dtile * 2 + hf] = *(const short8*)(vtbase + (size_t)(dtile * 16 + l4) * SEQ + hf * 32 + lg * 8);

  for (int t = 0; t < SEQ / 64; t++) {
    // QK^T: four 16(q) x 16(k) tiles from register K-frags
    f32x4 s[4];
    __builtin_amdgcn_s_setprio(1);
#pragma unroll
    for (int kt2 = 0; kt2 < 4; kt2++) {
      f32x4 acc = (f32x4){0.f, 0.f, 0.f, 0.f};
      acc = __builtin_amdgcn_mfma_f32_16x16x32_bf16(aq[0], kf[kt2 * 2 + 0], acc, 0, 0, 0);
      acc = __builtin_amdgcn_mfma_f32_16x16x32_bf16(aq[1], kf[kt2 * 2 + 1], acc, 0, 0, 0);
      s[kt2] = acc;
    }
    __builtin_amdgcn_s_setprio(0);

    // prefetch next K (latency hides under softmax+PV)
    if (t < SEQ / 64 - 1) {
      const int kv0n = (t + 1) * 64;
#pragma unroll
      for (int kt2 = 0; kt2 < 4; kt2++)
#pragma unroll
        for (int dt = 0; dt < 2; dt++)
          kf[kt2 * 2 + dt] = *(const short8*)(kbase + (size_t)(kv0n + kt2 * 16 + l4) * D_HEAD + dt * 32 + lg * 8);
    }

    // online softmax. Lane holds rows q=lg*4+r, col j=kt2*16+l4.
#pragma unroll
    for (int r = 0; r < 4; r++) {
      float mt = fmaxf(fmaxf(s[0][r], s[1][r]), fmaxf(s[2][r], s[3][r]));
#pragma unroll
      for (int mask = 1; mask <= 8; mask <<= 1)
        mt = fmaxf(mt, __shfl_xor(mt, mask, 64));
      const float mn   = fmaxf(m_[r], mt);
      const float corr = __expf(m_[r] - mn);
      float p[4];
      float rs = 0.f;
#pragma unroll
      for (int kt2 = 0; kt2 < 4; kt2++) { p[kt2] = __expf(s[kt2][r] - mn); rs += p[kt2]; }
      l_[r] = l_[r] * corr + rs;          // per-lane partial; no shfl here
      m_[r] = mn;
      o[0][r] *= corr; o[1][r] *= corr; o[2][r] *= corr; o[3][r] *= corr;
      const int qr = lg * 4 + r;
#pragma unroll
      for (int kt2 = 0; kt2 < 4; kt2++)
        P_lds[w][qr * 72 + kt2 * 16 + l4] = f2bf(p[kt2]);
    }
    // same-wave LDS write->read: lockstep wave + drained lgkm is sufficient
    asm volatile("s_waitcnt lgkmcnt(0)" ::: "memory");
    __builtin_amdgcn_sched_barrier(0);

    // PV: O[q][d] += P(16x64) * V(64x64); B-operands from registers
    const short8 pa0 = *(const short8*)&P_lds[w][l4 * 72 + lg * 8];
    const short8 pa1 = *(const short8*)&P_lds[w][l4 * 72 + 32 + lg * 8];
    __builtin_amdgcn_s_setprio(1);
#pragma unroll
    for (int dtile = 0; dtile < 4; dtile++) {
      o[dtile] = __builtin_amdgcn_mfma_f32_16x16x32_bf16(pa0, vf[dtile * 2 + 0], o[dtile], 0, 0, 0);
      o[dtile] = __builtin_amdgcn_mfma_f32_16x16x32_bf16(pa1, vf[dtile * 2 + 1], o[dtile], 0, 0, 0);
    }
    __builtin_amdgcn_s_setprio(0);

    // prefetch next V^T (vf consumed)
    if (t < SEQ / 64 - 1) {
      const int kv0n = (t + 1) * 64;
#pragma unroll
      for (int dtile = 0; dtile < 4; dtile++)
#pragma unroll
        for (int hf = 0; hf < 2; hf++)
          vf[dtile * 2 + hf] = *(const short8*)(vtbase + (size_t)(dtile * 16 + l4) * SEQ + kv0n + hf * 32 + lg * 8);
    }
  }

  // final: reduce per-lane l over the 16-lane column group
#pragma unroll
  for (int r = 0; r < 4; r++)
#pragma unroll
    for (int mask = 1; mask <= 8; mask <<= 1)
      l_[r] += __shfl_xor(l_[r], mask, 64);

  // epilogue: divide by l, write bf16 att[b][s][h*64+d]
  const int b_ = bh >> 3, h = bh & 7;
#pragma unroll
  for (int r = 0; r < 4; r++) {
    const int qrow = qb * 64 + w * 16 + lg * 4 + r;
    const float inv = 1.0f / l_[r];
    unsigned short* op = att + ((size_t)(b_ * SEQ + qrow)) * D_MODEL + h * D_HEAD;
#pragma unroll
    for (int dtile = 0; dtile < 4; dtile++)
      op[dtile * 16 + l4] = f2bf(o[dtile][r] * inv);
  }
}

// ---------------------------------------------------------------------------
// Kernel 4: output projection + bias + residual. grid = (ROWS/64, 8).
// ---------------------------------------------------------------------------
__global__ __launch_bounds__(256) void proj_mfma_kernel(const unsigned short* __restrict__ att,
                                                        const unsigned short* __restrict__ wot,
                                                        const float* __restrict__ bo,
                                                        const float* __restrict__ x,
                                                        float* __restrict__ out) {
  __shared__ __align__(16) unsigned short Bs[2][64 * 64];
  f32x4 acc[4];
#pragma unroll
  for (int i = 0; i < 4; i++) acc[i] = (f32x4){0.f, 0.f, 0.f, 0.f};
  bf16_gemm_lds(att, wot, Bs, acc, blockIdx.x, blockIdx.y);

  const int lane = threadIdx.x & 63, wv_ = threadIdx.x >> 6;
  const int l4 = lane & 15, lg = lane >> 4;
#pragma unroll
  for (int nt = 0; nt < 4; nt++) {
    const float bb = bo[blockIdx.y * 64 + nt * 16 + l4];
#pragma unroll
    for (int r = 0; r < 4; r++) {
      const int row = blockIdx.x * 64 + wv_ * 16 + lg * 4 + r;
      const size_t off = (size_t)row * D_MODEL + blockIdx.y * 64 + nt * 16 + l4;
      out[off] = acc[nt][r] + bb + x[off];
    }
  }
}

// ---------------------------------------------------------------------------
extern "C" void kernel_launch(void* const* d_in, const int* in_sizes, int n_in,
                              void* d_out, int out_size, void* d_ws, size_t ws_size,
                              hipStream_t stream) {
  const float* x     = (const float*)d_in[0];
  const float* wq    = (const float*)d_in[1];
  const float* bq    = (const float*)d_in[2];
  const float* wk    = (const float*)d_in[3];
  const float* bk    = (const float*)d_in[4];
  const float* wv    = (const float*)d_in[5];
  const float* bv    = (const float*)d_in[6];
  const float* wo    = (const float*)d_in[7];
  const float* bo    = (const float*)d_in[8];
  const float* gamma = (const float*)d_in[9];
  const float* beta  = (const float*)d_in[10];
  float* out = (float*)d_out;

  // bf16 workspace: xn | q | k | v (4 x 8 MiB) | wt (2 MiB) | vt (8 MiB); att = xn
  unsigned short* xn  = (unsigned short*)d_ws;
  unsigned short* q   = xn + (size_t)ROWS * D_MODEL;
  unsigned short* k   = q  + (size_t)ROWS * D_MODEL;
  unsigned short* v   = k  + (size_t)ROWS * D_MODEL;
  unsigned short* wt  = v  + (size_t)ROWS * D_MODEL;            // [4][512][512] n-major
  unsigned short* vt  = wt + (size_t)4 * D_MODEL * D_MODEL;     // [32][64][SEQ]
  unsigned short* att = xn;  // xn dead after qkv

  wtrans_kernel<<<dim3(8, 8, 4), 256, 0, stream>>>(wq, wk, wv, wo, wt);
  ln_kernel<<<ROWS, 128, 0, stream>>>(x, gamma, beta, xn);
  qkv_mfma_kernel<<<dim3(ROWS / 64, N_HEADS, 3), 256, 0, stream>>>(
      xn, wt, bq, bk, bv, q, k, v);
  vtrans_kernel<<<dim3(SEQ / 64, BATCH * N_HEADS), 256, 0, stream>>>(v, vt);
  attn_mfma_kernel<<<1024, 256, 0, stream>>>(q, k, vt, att);
  proj_mfma_kernel<<<dim3(ROWS / 64, D_MODEL / 64), 256, 0, stream>>>(
      att, wt + (size_t)3 * D_MODEL * D_MODEL, bo, x, out);
}

// Round 10
// 292.919 us; speedup vs baseline: 1.3277x; 1.2800x over previous
//
#include <hip/hip_runtime.h>
#include <hip/hip_bf16.h>

#define D_MODEL 512
#define N_HEADS 8
#define D_HEAD  64
#define SEQ     2048
#define BATCH   4
#define ROWS    (BATCH * SEQ)   /* 8192 */
#define EPS     1e-5f
#define SCALE   0.125f
#define QSCALE  0.18033688011112042f  /* 0.125 * log2(e): scores in log2 domain */

typedef __attribute__((ext_vector_type(8))) short short8;   // 8 bf16 (4 VGPRs)
typedef __attribute__((ext_vector_type(4))) float f32x4;    // MFMA C/D

__device__ __forceinline__ unsigned short f2bf(float f) {
  return __builtin_bit_cast(unsigned short, __float2bfloat16(f));  // RNE
}

// ---------------------------------------------------------------------------
// Kernel 0: one-time W transpose+convert: fp32 [K][N] -> bf16 Wt[N][K].
// ---------------------------------------------------------------------------
__global__ __launch_bounds__(256) void wtrans_kernel(const float* __restrict__ wq,
                                                     const float* __restrict__ wk,
                                                     const float* __restrict__ wv,
                                                     const float* __restrict__ wo,
                                                     unsigned short* __restrict__ wt) {
  __shared__ float T[64][68];
  const float* src;
  switch (blockIdx.z) { case 0: src = wq; break; case 1: src = wk; break;
                        case 2: src = wv; break; default: src = wo; }
  const int tid = threadIdx.x;
  const int bk = blockIdx.x, bn = blockIdx.y;
  {
    const int k = tid >> 2, n0 = (tid & 3) * 16;
#pragma unroll
    for (int j = 0; j < 4; j++) {
      const float4 f = *(const float4*)(src + (size_t)(bk * 64 + k) * D_MODEL + bn * 64 + n0 + j * 4);
      *(float4*)&T[k][n0 + j * 4] = f;
    }
  }
  __syncthreads();
  {
    const int n = tid >> 2, k0 = (tid & 3) * 16;
    short8 t0, t1;
#pragma unroll
    for (int j = 0; j < 8; j++) t0[j] = (short)f2bf(T[k0 + j][n]);
#pragma unroll
    for (int j = 0; j < 8; j++) t1[j] = (short)f2bf(T[k0 + 8 + j][n]);
    unsigned short* dst = wt + (size_t)blockIdx.z * D_MODEL * D_MODEL
                             + (size_t)(bn * 64 + n) * D_MODEL + bk * 64 + k0;
    *(short8*)dst = t0;
    *(short8*)(dst + 8) = t1;
  }
}

// ---------------------------------------------------------------------------
// Kernel 1: LayerNorm. fp32 math (known-good), bf16 output.
// ---------------------------------------------------------------------------
__global__ __launch_bounds__(128) void ln_kernel(const float* __restrict__ x,
                                                 const float* __restrict__ gamma,
                                                 const float* __restrict__ beta,
                                                 unsigned short* __restrict__ xn) {
  const int row = blockIdx.x;
  const int t   = threadIdx.x;
  const float4 v = ((const float4*)(x + (size_t)row * D_MODEL))[t];
  float s  = v.x + v.y + v.z + v.w;
  float s2 = v.x*v.x + v.y*v.y + v.z*v.z + v.w*v.w;
#pragma unroll
  for (int o = 32; o > 0; o >>= 1) {
    s  += __shfl_down(s,  o, 64);
    s2 += __shfl_down(s2, o, 64);
  }
  __shared__ float ps[2], ps2[2];
  if ((t & 63) == 0) { ps[t >> 6] = s; ps2[t >> 6] = s2; }
  __syncthreads();
  s  = ps[0] + ps[1];
  s2 = ps2[0] + ps2[1];
  const float mu  = s * (1.0f / D_MODEL);
  const float var = s2 * (1.0f / D_MODEL) - mu * mu;
  const float rs  = rsqrtf(var + EPS);
  const float4 g = ((const float4*)gamma)[t];
  const float4 b = ((const float4*)beta)[t];
  ushort4 o;
  o.x = f2bf((v.x - mu) * rs * g.x + b.x);
  o.y = f2bf((v.y - mu) * rs * g.y + b.y);
  o.z = f2bf((v.z - mu) * rs * g.z + b.z);
  o.w = f2bf((v.w - mu) * rs * g.w + b.w);
  ((ushort4*)(xn + (size_t)row * D_MODEL))[t] = o;
}

// ---------------------------------------------------------------------------
// Shared bf16-MFMA GEMM (R9-measured, unchanged): C[64x64] = A[64x512]*Wt.
// BK=64, double-buffered LDS, XOR-granule swizzle both sides.
// ---------------------------------------------------------------------------
__device__ __forceinline__ void bf16_gemm_lds(const unsigned short* __restrict__ A,
                                              const unsigned short* __restrict__ Wt,
                                              unsigned short (&Bs)[2][64 * 64],
                                              f32x4 (&acc)[4],
                                              int bm, int bn) {
  const int tid = threadIdx.x, lane = tid & 63;
  const int l4 = lane & 15, lg = lane >> 4, w = tid >> 6;

  short8 af[16];
  const unsigned short* ap = A + (size_t)(bm * 64 + w * 16 + l4) * D_MODEL + lg * 8;
#pragma unroll
  for (int kt8 = 0; kt8 < 16; kt8++) af[kt8] = *(const short8*)(ap + kt8 * 32);

  const int n = tid >> 2, c = tid & 3;
  const unsigned short* bsrc = Wt + (size_t)(bn * 64 + n) * D_MODEL;
  const int g0 = (2 * c)     ^ (n & 7);
  const int g1 = (2 * c + 1) ^ (n & 7);

  short8 r0 = *(const short8*)(bsrc + (2 * c) * 8);
  short8 r1 = *(const short8*)(bsrc + (2 * c + 1) * 8);
  *(short8*)&Bs[0][n * 64 + g0 * 8] = r0;
  *(short8*)&Bs[0][n * 64 + g1 * 8] = r1;
  __syncthreads();

  int cur = 0;
  for (int kt = 0; kt < 8; kt++) {
    if (kt < 7) {
      r0 = *(const short8*)(bsrc + (kt + 1) * 64 + (2 * c) * 8);
      r1 = *(const short8*)(bsrc + (kt + 1) * 64 + (2 * c + 1) * 8);
    }
#pragma unroll
    for (int dt = 0; dt < 2; dt++) {
#pragma unroll
      for (int nt = 0; nt < 4; nt++) {
        const int row = nt * 16 + l4;
        const short8 b = *(const short8*)&Bs[cur][row * 64 + ((dt * 4 + lg) ^ (l4 & 7)) * 8];
        acc[nt] = __builtin_amdgcn_mfma_f32_16x16x32_bf16(af[kt * 2 + dt], b, acc[nt], 0, 0, 0);
      }
    }
    if (kt < 7) {
      *(short8*)&Bs[cur ^ 1][n * 64 + g0 * 8] = r0;
      *(short8*)&Bs[cur ^ 1][n * 64 + g1 * 8] = r1;
    }
    __syncthreads();
    cur ^= 1;
  }
}

// ---------------------------------------------------------------------------
// Kernel 2: QKV projection. q pre-scaled by QSCALE (= scale * log2e) so the
// attention softmax runs natively in the exp2 domain.
// ---------------------------------------------------------------------------
__global__ __launch_bounds__(256) void qkv_mfma_kernel(const unsigned short* __restrict__ xn,
                                                       const unsigned short* __restrict__ wt,
                                                       const float* __restrict__ bq,
                                                       const float* __restrict__ bk_,
                                                       const float* __restrict__ bv_,
                                                       unsigned short* __restrict__ qo,
                                                       unsigned short* __restrict__ ko,
                                                       unsigned short* __restrict__ vo) {
  __shared__ __align__(16) unsigned short Bs[2][64 * 64];
  const int z = blockIdx.z;
  const unsigned short* W = wt + (size_t)z * D_MODEL * D_MODEL;
  const float* bias = (z == 0) ? bq : ((z == 1) ? bk_ : bv_);
  unsigned short* out = (z == 0) ? qo : ((z == 1) ? ko : vo);
  const float scale = (z == 0) ? QSCALE : 1.0f;

  f32x4 acc[4];
#pragma unroll
  for (int i = 0; i < 4; i++) acc[i] = (f32x4){0.f, 0.f, 0.f, 0.f};
  bf16_gemm_lds(xn, W, Bs, acc, blockIdx.x, blockIdx.y);

  const int lane = threadIdx.x & 63, wv_ = threadIdx.x >> 6;
  const int l4 = lane & 15, lg = lane >> 4;
  const int h = blockIdx.y;
#pragma unroll
  for (int nt = 0; nt < 4; nt++) {
    const float bb = bias[h * 64 + nt * 16 + l4];
#pragma unroll
    for (int r = 0; r < 4; r++) {
      const int row = blockIdx.x * 64 + wv_ * 16 + lg * 4 + r;
      const int b_  = row >> 11;          // row / SEQ
      const int s   = row & (SEQ - 1);    // row % SEQ
      out[((size_t)(b_ * N_HEADS + h) * SEQ + s) * D_HEAD + nt * 16 + l4] =
          f2bf((acc[nt][r] + bb) * scale);
    }
  }
}

// ---------------------------------------------------------------------------
// Kernel 3: MFMA flash attention — R8 structure (best measured, 172 us):
// K reg-prefetched from L2; V LDS-staged (transposed); 2 barriers per
// 64-kv tile. New this round: exp2-domain softmax (q pre-scaled by log2e),
// defer-max rescale skip (THR=8), end-only l reduction.
// ---------------------------------------------------------------------------
__global__ __launch_bounds__(256) void attn_mfma_kernel(const unsigned short* __restrict__ q,
                                                        const unsigned short* __restrict__ k,
                                                        const unsigned short* __restrict__ v,
                                                        unsigned short* __restrict__ att) {
  __shared__ __align__(16) unsigned short Vt_lds[64 * 72];   // V^T [d][j], pad->72
  __shared__ __align__(16) unsigned short P_lds[4][16 * 72]; // per wave [q][j]

  const int tid  = threadIdx.x;
  const int lane = tid & 63;
  const int w    = tid >> 6;
  const int l4   = lane & 15;     // C/D col | A row | B row
  const int lg   = lane >> 4;     // k-slice group

  // XCD-chunked swizzle: each XCD's 128 blocks = 4 complete heads.
  const int swz = (blockIdx.x & 7) * 128 + (blockIdx.x >> 3);
  const int qb  = swz & 31;       // q-block (64 rows)
  const int bh  = swz >> 5;       // batch*head

  const unsigned short* qbase = q + (size_t)bh * SEQ * D_HEAD;
  const unsigned short* kbase = k + (size_t)bh * SEQ * D_HEAD;
  const unsigned short* vbase = v + (size_t)bh * SEQ * D_HEAD;

  // Q A-frags (pre-scaled by scale*log2e upstream)
  short8 aq[2];
  {
    const unsigned short* qp = qbase + (size_t)(qb * 64 + w * 16 + l4) * D_HEAD + lg * 8;
    aq[0] = *(const short8*)(qp);
    aq[1] = *(const short8*)(qp + 32);
  }

  f32x4 o[4];
#pragma unroll
  for (int i = 0; i < 4; i++) o[i] = (f32x4){0.f, 0.f, 0.f, 0.f};
  float m_[4] = {-1e30f, -1e30f, -1e30f, -1e30f};
  float l_[4] = {0.f, 0.f, 0.f, 0.f};   // per-lane partials, reduced at end

  // V staging role: thread stages V[j=vj][d = vd0..vd0+15]
  const int vj  = tid & 63;
  const int vd0 = (tid >> 6) * 16;

  // register prefetch (tile 0)
  short8 kf[8];   // [kt2*2+dt] = K[kt2*16+l4][dt*32+lg*8+..]
  short8 vf[2];
#pragma unroll
  for (int kt2 = 0; kt2 < 4; kt2++)
#pragma unroll
    for (int dt = 0; dt < 2; dt++)
      kf[kt2 * 2 + dt] = *(const short8*)(kbase + (size_t)(kt2 * 16 + l4) * D_HEAD + dt * 32 + lg * 8);
  vf[0] = *(const short8*)(vbase + (size_t)vj * D_HEAD + vd0);
  vf[1] = *(const short8*)(vbase + (size_t)vj * D_HEAD + vd0 + 8);

  for (int t = 0; t < SEQ / 64; t++) {
    __syncthreads();   // Vt of previous tile fully consumed
    {  // write V^T tile from prefetched regs (2 lanes/bank: free)
#pragma unroll
      for (int i = 0; i < 2; i++)
#pragma unroll
        for (int e = 0; e < 8; e++)
          Vt_lds[(vd0 + i * 8 + e) * 72 + vj] = (unsigned short)vf[i][e];
    }
    __syncthreads();

    // QK^T: four 16(q) x 16(k) tiles from register K-frags
    f32x4 s[4];
    __builtin_amdgcn_s_setprio(1);
#pragma unroll
    for (int kt2 = 0; kt2 < 4; kt2++) {
      f32x4 acc = (f32x4){0.f, 0.f, 0.f, 0.f};
      acc = __builtin_amdgcn_mfma_f32_16x16x32_bf16(aq[0], kf[kt2 * 2 + 0], acc, 0, 0, 0);
      acc = __builtin_amdgcn_mfma_f32_16x16x32_bf16(aq[1], kf[kt2 * 2 + 1], acc, 0, 0, 0);
      s[kt2] = acc;
    }
    __builtin_amdgcn_s_setprio(0);

    // prefetch next K/V (latency hides under softmax+PV+barrier)
    if (t < SEQ / 64 - 1) {
      const int kv0n = (t + 1) * 64;
#pragma unroll
      for (int kt2 = 0; kt2 < 4; kt2++)
#pragma unroll
        for (int dt = 0; dt < 2; dt++)
          kf[kt2 * 2 + dt] = *(const short8*)(kbase + (size_t)(kv0n + kt2 * 16 + l4) * D_HEAD + dt * 32 + lg * 8);
      vf[0] = *(const short8*)(vbase + (size_t)(kv0n + vj) * D_HEAD + vd0);
      vf[1] = *(const short8*)(vbase + (size_t)(kv0n + vj) * D_HEAD + vd0 + 8);
    }

    // --- online softmax (exp2 domain). Lane: rows q=lg*4+r, col j=kt2*16+l4.
    float mt[4];
#pragma unroll
    for (int r = 0; r < 4; r++) {
      float m0 = fmaxf(fmaxf(s[0][r], s[1][r]), fmaxf(s[2][r], s[3][r]));
#pragma unroll
      for (int mask = 1; mask <= 8; mask <<= 1)
        m0 = fmaxf(m0, __shfl_xor(m0, mask, 64));
      mt[r] = m0;
    }
    // defer-max: skip the o-rescale while the running max is stable (THR=8)
    bool stable = true;
#pragma unroll
    for (int r = 0; r < 4; r++) stable &= (mt[r] <= m_[r] + 8.0f);
    if (!__all((int)stable)) {
#pragma unroll
      for (int r = 0; r < 4; r++) {
        const float mn   = fmaxf(m_[r], mt[r]);
        const float corr = exp2f(m_[r] - mn);
        l_[r] *= corr;
        o[0][r] *= corr; o[1][r] *= corr; o[2][r] *= corr; o[3][r] *= corr;
        m_[r] = mn;
      }
    }
#pragma unroll
    for (int r = 0; r < 4; r++) {
      float p[4];
      float rs = 0.f;
#pragma unroll
      for (int kt2 = 0; kt2 < 4; kt2++) { p[kt2] = exp2f(s[kt2][r] - m_[r]); rs += p[kt2]; }
      l_[r] += rs;                     // per-lane partial; reduced at end
      const int qr = lg * 4 + r;
#pragma unroll
      for (int kt2 = 0; kt2 < 4; kt2++)
        P_lds[w][qr * 72 + kt2 * 16 + l4] = f2bf(p[kt2]);
    }
    // same-wave LDS write->read: lockstep wave + drained lgkm is sufficient
    asm volatile("s_waitcnt lgkmcnt(0)" ::: "memory");
    __builtin_amdgcn_sched_barrier(0);

    // PV: O[q][d] += P(16x64) * V(64x64)
    const short8 pa0 = *(const short8*)&P_lds[w][l4 * 72 + lg * 8];
    const short8 pa1 = *(const short8*)&P_lds[w][l4 * 72 + 32 + lg * 8];
    __builtin_amdgcn_s_setprio(1);
#pragma unroll
    for (int dtile = 0; dtile < 4; dtile++) {
      const short8 bv0 = *(const short8*)&Vt_lds[(dtile * 16 + l4) * 72 + lg * 8];
      const short8 bv1 = *(const short8*)&Vt_lds[(dtile * 16 + l4) * 72 + 32 + lg * 8];
      o[dtile] = __builtin_amdgcn_mfma_f32_16x16x32_bf16(pa0, bv0, o[dtile], 0, 0, 0);
      o[dtile] = __builtin_amdgcn_mfma_f32_16x16x32_bf16(pa1, bv1, o[dtile], 0, 0, 0);
    }
    __builtin_amdgcn_s_setprio(0);
  }

  // final: reduce per-lane l over the 16-lane column group
#pragma unroll
  for (int r = 0; r < 4; r++)
#pragma unroll
    for (int mask = 1; mask <= 8; mask <<= 1)
      l_[r] += __shfl_xor(l_[r], mask, 64);

  // epilogue: divide by l, write bf16 att[b][s][h*64+d]
  const int b_ = bh >> 3, h = bh & 7;
#pragma unroll
  for (int r = 0; r < 4; r++) {
    const int qrow = qb * 64 + w * 16 + lg * 4 + r;
    const float inv = 1.0f / l_[r];
    unsigned short* op = att + ((size_t)(b_ * SEQ + qrow)) * D_MODEL + h * D_HEAD;
#pragma unroll
    for (int dtile = 0; dtile < 4; dtile++)
      op[dtile * 16 + l4] = f2bf(o[dtile][r] * inv);
  }
}

// ---------------------------------------------------------------------------
// Kernel 4: output projection + bias + residual. grid = (ROWS/64, 8).
// ---------------------------------------------------------------------------
__global__ __launch_bounds__(256) void proj_mfma_kernel(const unsigned short* __restrict__ att,
                                                        const unsigned short* __restrict__ wot,
                                                        const float* __restrict__ bo,
                                                        const float* __restrict__ x,
                                                        float* __restrict__ out) {
  __shared__ __align__(16) unsigned short Bs[2][64 * 64];
  f32x4 acc[4];
#pragma unroll
  for (int i = 0; i < 4; i++) acc[i] = (f32x4){0.f, 0.f, 0.f, 0.f};
  bf16_gemm_lds(att, wot, Bs, acc, blockIdx.x, blockIdx.y);

  const int lane = threadIdx.x & 63, wv_ = threadIdx.x >> 6;
  const int l4 = lane & 15, lg = lane >> 4;
#pragma unroll
  for (int nt = 0; nt < 4; nt++) {
    const float bb = bo[blockIdx.y * 64 + nt * 16 + l4];
#pragma unroll
    for (int r = 0; r < 4; r++) {
      const int row = blockIdx.x * 64 + wv_ * 16 + lg * 4 + r;
      const size_t off = (size_t)row * D_MODEL + blockIdx.y * 64 + nt * 16 + l4;
      out[off] = acc[nt][r] + bb + x[off];
    }
  }
}

// ---------------------------------------------------------------------------
extern "C" void kernel_launch(void* const* d_in, const int* in_sizes, int n_in,
                              void* d_out, int out_size, void* d_ws, size_t ws_size,
                              hipStream_t stream) {
  const float* x     = (const float*)d_in[0];
  const float* wq    = (const float*)d_in[1];
  const float* bq    = (const float*)d_in[2];
  const float* wk    = (const float*)d_in[3];
  const float* bk    = (const float*)d_in[4];
  const float* wv    = (const float*)d_in[5];
  const float* bv    = (const float*)d_in[6];
  const float* wo    = (const float*)d_in[7];
  const float* bo    = (const float*)d_in[8];
  const float* gamma = (const float*)d_in[9];
  const float* beta  = (const float*)d_in[10];
  float* out = (float*)d_out;

  // bf16 workspace: xn | q | k | v (4 x 8 MiB) | wt (2 MiB); att = xn
  unsigned short* xn  = (unsigned short*)d_ws;
  unsigned short* q   = xn + (size_t)ROWS * D_MODEL;
  unsigned short* k   = q  + (size_t)ROWS * D_MODEL;
  unsigned short* v   = k  + (size_t)ROWS * D_MODEL;
  unsigned short* wt  = v  + (size_t)ROWS * D_MODEL;   // [4][512][512] n-major
  unsigned short* att = xn;  // xn dead after qkv

  wtrans_kernel<<<dim3(8, 8, 4), 256, 0, stream>>>(wq, wk, wv, wo, wt);
  ln_kernel<<<ROWS, 128, 0, stream>>>(x, gamma, beta, xn);
  qkv_mfma_kernel<<<dim3(ROWS / 64, N_HEADS, 3), 256, 0, stream>>>(
      xn, wt, bq, bk, bv, q, k, v);
  attn_mfma_kernel<<<1024, 256, 0, stream>>>(q, k, v, att);
  proj_mfma_kernel<<<dim3(ROWS / 64, D_MODEL / 64), 256, 0, stream>>>(
      att, wt + (size_t)3 * D_MODEL * D_MODEL, bo, x, out);
}

// Round 12
// 290.020 us; speedup vs baseline: 1.3409x; 1.0100x over previous
//
#include <hip/hip_runtime.h>
#include <hip/hip_bf16.h>

#define D_MODEL 512
#define N_HEADS 8
#define D_HEAD  64
#define SEQ     2048
#define BATCH   4
#define ROWS    (BATCH * SEQ)   /* 8192 */
#define EPS     1e-5f
#define SCALE   0.125f
#define QSCALE  0.18033688011112042f  /* 0.125 * log2(e): scores in log2 domain */

typedef __attribute__((ext_vector_type(8))) short short8;   // 8 bf16 (4 VGPRs)
typedef __attribute__((ext_vector_type(4))) float f32x4;    // MFMA C/D

__device__ __forceinline__ unsigned short f2bf(float f) {
  return __builtin_bit_cast(unsigned short, __float2bfloat16(f));  // RNE
}

// ---------------------------------------------------------------------------
// Kernel 0: one-time W transpose+convert: fp32 [K][N] -> bf16 Wt[N][K].
// ---------------------------------------------------------------------------
__global__ __launch_bounds__(256) void wtrans_kernel(const float* __restrict__ wq,
                                                     const float* __restrict__ wk,
                                                     const float* __restrict__ wv,
                                                     const float* __restrict__ wo,
                                                     unsigned short* __restrict__ wt) {
  __shared__ float T[64][68];
  const float* src;
  switch (blockIdx.z) { case 0: src = wq; break; case 1: src = wk; break;
                        case 2: src = wv; break; default: src = wo; }
  const int tid = threadIdx.x;
  const int bk = blockIdx.x, bn = blockIdx.y;
  {
    const int k = tid >> 2, n0 = (tid & 3) * 16;
#pragma unroll
    for (int j = 0; j < 4; j++) {
      const float4 f = *(const float4*)(src + (size_t)(bk * 64 + k) * D_MODEL + bn * 64 + n0 + j * 4);
      *(float4*)&T[k][n0 + j * 4] = f;
    }
  }
  __syncthreads();
  {
    const int n = tid >> 2, k0 = (tid & 3) * 16;
    short8 t0, t1;
#pragma unroll
    for (int j = 0; j < 8; j++) t0[j] = (short)f2bf(T[k0 + j][n]);
#pragma unroll
    for (int j = 0; j < 8; j++) t1[j] = (short)f2bf(T[k0 + 8 + j][n]);
    unsigned short* dst = wt + (size_t)blockIdx.z * D_MODEL * D_MODEL
                             + (size_t)(bn * 64 + n) * D_MODEL + bk * 64 + k0;
    *(short8*)dst = t0;
    *(short8*)(dst + 8) = t1;
  }
}

// ---------------------------------------------------------------------------
// Kernel 1: LayerNorm. fp32 math (known-good), bf16 output.
// ---------------------------------------------------------------------------
__global__ __launch_bounds__(128) void ln_kernel(const float* __restrict__ x,
                                                 const float* __restrict__ gamma,
                                                 const float* __restrict__ beta,
                                                 unsigned short* __restrict__ xn) {
  const int row = blockIdx.x;
  const int t   = threadIdx.x;
  const float4 v = ((const float4*)(x + (size_t)row * D_MODEL))[t];
  float s  = v.x + v.y + v.z + v.w;
  float s2 = v.x*v.x + v.y*v.y + v.z*v.z + v.w*v.w;
#pragma unroll
  for (int o = 32; o > 0; o >>= 1) {
    s  += __shfl_down(s,  o, 64);
    s2 += __shfl_down(s2, o, 64);
  }
  __shared__ float ps[2], ps2[2];
  if ((t & 63) == 0) { ps[t >> 6] = s; ps2[t >> 6] = s2; }
  __syncthreads();
  s  = ps[0] + ps[1];
  s2 = ps2[0] + ps2[1];
  const float mu  = s * (1.0f / D_MODEL);
  const float var = s2 * (1.0f / D_MODEL) - mu * mu;
  const float rs  = rsqrtf(var + EPS);
  const float4 g = ((const float4*)gamma)[t];
  const float4 b = ((const float4*)beta)[t];
  ushort4 o;
  o.x = f2bf((v.x - mu) * rs * g.x + b.x);
  o.y = f2bf((v.y - mu) * rs * g.y + b.y);
  o.z = f2bf((v.z - mu) * rs * g.z + b.z);
  o.w = f2bf((v.w - mu) * rs * g.w + b.w);
  ((ushort4*)(xn + (size_t)row * D_MODEL))[t] = o;
}

// ---------------------------------------------------------------------------
// Shared bf16-MFMA GEMM (measured-good, unchanged): C[64x64] = A[64x512]*Wt.
// BK=64, double-buffered LDS, XOR-granule swizzle both sides.
// ---------------------------------------------------------------------------
__device__ __forceinline__ void bf16_gemm_lds(const unsigned short* __restrict__ A,
                                              const unsigned short* __restrict__ Wt,
                                              unsigned short (&Bs)[2][64 * 64],
                                              f32x4 (&acc)[4],
                                              int bm, int bn) {
  const int tid = threadIdx.x, lane = tid & 63;
  const int l4 = lane & 15, lg = lane >> 4, w = tid >> 6;

  short8 af[16];
  const unsigned short* ap = A + (size_t)(bm * 64 + w * 16 + l4) * D_MODEL + lg * 8;
#pragma unroll
  for (int kt8 = 0; kt8 < 16; kt8++) af[kt8] = *(const short8*)(ap + kt8 * 32);

  const int n = tid >> 2, c = tid & 3;
  const unsigned short* bsrc = Wt + (size_t)(bn * 64 + n) * D_MODEL;
  const int g0 = (2 * c)     ^ (n & 7);
  const int g1 = (2 * c + 1) ^ (n & 7);

  short8 r0 = *(const short8*)(bsrc + (2 * c) * 8);
  short8 r1 = *(const short8*)(bsrc + (2 * c + 1) * 8);
  *(short8*)&Bs[0][n * 64 + g0 * 8] = r0;
  *(short8*)&Bs[0][n * 64 + g1 * 8] = r1;
  __syncthreads();

  int cur = 0;
  for (int kt = 0; kt < 8; kt++) {
    if (kt < 7) {
      r0 = *(const short8*)(bsrc + (kt + 1) * 64 + (2 * c) * 8);
      r1 = *(const short8*)(bsrc + (kt + 1) * 64 + (2 * c + 1) * 8);
    }
#pragma unroll
    for (int dt = 0; dt < 2; dt++) {
#pragma unroll
      for (int nt = 0; nt < 4; nt++) {
        const int row = nt * 16 + l4;
        const short8 b = *(const short8*)&Bs[cur][row * 64 + ((dt * 4 + lg) ^ (l4 & 7)) * 8];
        acc[nt] = __builtin_amdgcn_mfma_f32_16x16x32_bf16(af[kt * 2 + dt], b, acc[nt], 0, 0, 0);
      }
    }
    if (kt < 7) {
      *(short8*)&Bs[cur ^ 1][n * 64 + g0 * 8] = r0;
      *(short8*)&Bs[cur ^ 1][n * 64 + g1 * 8] = r1;
    }
    __syncthreads();
    cur ^= 1;
  }
}

// ---------------------------------------------------------------------------
// Kernel 2: QKV projection. q pre-scaled by QSCALE (= scale * log2e).
// ---------------------------------------------------------------------------
__global__ __launch_bounds__(256) void qkv_mfma_kernel(const unsigned short* __restrict__ xn,
                                                       const unsigned short* __restrict__ wt,
                                                       const float* __restrict__ bq,
                                                       const float* __restrict__ bk_,
                                                       const float* __restrict__ bv_,
                                                       unsigned short* __restrict__ qo,
                                                       unsigned short* __restrict__ ko,
                                                       unsigned short* __restrict__ vo) {
  __shared__ __align__(16) unsigned short Bs[2][64 * 64];
  const int z = blockIdx.z;
  const unsigned short* W = wt + (size_t)z * D_MODEL * D_MODEL;
  const float* bias = (z == 0) ? bq : ((z == 1) ? bk_ : bv_);
  unsigned short* out = (z == 0) ? qo : ((z == 1) ? ko : vo);
  const float scale = (z == 0) ? QSCALE : 1.0f;

  f32x4 acc[4];
#pragma unroll
  for (int i = 0; i < 4; i++) acc[i] = (f32x4){0.f, 0.f, 0.f, 0.f};
  bf16_gemm_lds(xn, W, Bs, acc, blockIdx.x, blockIdx.y);

  const int lane = threadIdx.x & 63, wv_ = threadIdx.x >> 6;
  const int l4 = lane & 15, lg = lane >> 4;
  const int h = blockIdx.y;
#pragma unroll
  for (int nt = 0; nt < 4; nt++) {
    const float bb = bias[h * 64 + nt * 16 + l4];
#pragma unroll
    for (int r = 0; r < 4; r++) {
      const int row = blockIdx.x * 64 + wv_ * 16 + lg * 4 + r;
      const int b_  = row >> 11;          // row / SEQ
      const int s   = row & (SEQ - 1);    // row % SEQ
      out[((size_t)(b_ * N_HEADS + h) * SEQ + s) * D_HEAD + nt * 16 + l4] =
          f2bf((acc[nt][r] + bb) * scale);
    }
  }
}

// ---------------------------------------------------------------------------
// Kernel 3: MFMA flash attention, KVBLK=128.
// Halves per-unit-work serial overhead vs KVB=64: 16 barrier-pairs total,
// half the max-reduce shfls, defer-checks, lgkm drains. K reg-prefetched
// (16 frags; kf dead at prefetch point -> reg reuse); V reg-prefetched then
// LDS-staged transposed, stride 136 (same bank-residue class as measured
// stride-72). exp2-domain softmax + defer-max (THR=8).
// ---------------------------------------------------------------------------
#define KVB 128
__global__ __launch_bounds__(256) void attn_mfma_kernel(const unsigned short* __restrict__ q,
                                                        const unsigned short* __restrict__ k,
                                                        const unsigned short* __restrict__ v,
                                                        unsigned short* __restrict__ att) {
  __shared__ __align__(16) unsigned short Vt_lds[64 * 136];   // V^T [d][j 0..127]
  __shared__ __align__(16) unsigned short P_lds[4][16 * 136]; // per wave [q][j]

  const int tid  = threadIdx.x;
  const int lane = tid & 63;
  const int w    = tid >> 6;
  const int l4   = lane & 15;     // C/D col | A row | B row
  const int lg   = lane >> 4;     // k-slice group

  // XCD-chunked swizzle: each XCD's 128 blocks = 4 complete heads.
  const int swz = (blockIdx.x & 7) * 128 + (blockIdx.x >> 3);
  const int qb  = swz & 31;       // q-block (64 rows)
  const int bh  = swz >> 5;       // batch*head

  const unsigned short* qbase = q + (size_t)bh * SEQ * D_HEAD;
  const unsigned short* kbase = k + (size_t)bh * SEQ * D_HEAD;
  const unsigned short* vbase = v + (size_t)bh * SEQ * D_HEAD;

  // Q A-frags (pre-scaled by scale*log2e upstream)
  short8 aq[2];
  {
    const unsigned short* qp = qbase + (size_t)(qb * 64 + w * 16 + l4) * D_HEAD + lg * 8;
    aq[0] = *(const short8*)(qp);
    aq[1] = *(const short8*)(qp + 32);
  }

  f32x4 o[4];
#pragma unroll
  for (int i = 0; i < 4; i++) o[i] = (f32x4){0.f, 0.f, 0.f, 0.f};
  float m_[4] = {-1e30f, -1e30f, -1e30f, -1e30f};
  float l_[4] = {0.f, 0.f, 0.f, 0.f};   // per-lane partials, reduced at end

  // V staging role: thread stages V[j=vj][d = vd0..vd0+31]
  const int vj  = tid & 127;
  const int vd0 = (tid >> 7) * 32;

  // register prefetch (tile 0)
  short8 kf[16];  // [kt2*2+dt] = K[kt2*16+l4][dt*32+lg*8+..], kt2 0..7
  short8 vf[4];   // V[vj][vd0 + n*8 ..]
#pragma unroll
  for (int kt2 = 0; kt2 < 8; kt2++)
#pragma unroll
    for (int dt = 0; dt < 2; dt++)
      kf[kt2 * 2 + dt] = *(const short8*)(kbase + (size_t)(kt2 * 16 + l4) * D_HEAD + dt * 32 + lg * 8);
#pragma unroll
  for (int n = 0; n < 4; n++)
    vf[n] = *(const short8*)(vbase + (size_t)vj * D_HEAD + vd0 + n * 8);

  for (int t = 0; t < SEQ / KVB; t++) {
    __syncthreads();   // Vt of previous tile fully consumed
    {  // write V^T tile from prefetched regs (2 lanes/bank: free)
#pragma unroll
      for (int n = 0; n < 4; n++)
#pragma unroll
        for (int e = 0; e < 8; e++)
          Vt_lds[(vd0 + n * 8 + e) * 136 + vj] = (unsigned short)vf[n][e];
    }
    __syncthreads();

    // QK^T: eight 16(q) x 16(k) tiles from register K-frags
    f32x4 s[8];
    __builtin_amdgcn_s_setprio(1);
#pragma unroll
    for (int kt2 = 0; kt2 < 8; kt2++) {
      f32x4 acc = (f32x4){0.f, 0.f, 0.f, 0.f};
      acc = __builtin_amdgcn_mfma_f32_16x16x32_bf16(aq[0], kf[kt2 * 2 + 0], acc, 0, 0, 0);
      acc = __builtin_amdgcn_mfma_f32_16x16x32_bf16(aq[1], kf[kt2 * 2 + 1], acc, 0, 0, 0);
      s[kt2] = acc;
    }
    __builtin_amdgcn_s_setprio(0);

    // prefetch next K/V (kf/vf dead here -> regs reuse; latency hides
    // under softmax+PV+barrier)
    if (t < SEQ / KVB - 1) {
      const int kv0n = (t + 1) * KVB;
#pragma unroll
      for (int kt2 = 0; kt2 < 8; kt2++)
#pragma unroll
        for (int dt = 0; dt < 2; dt++)
          kf[kt2 * 2 + dt] = *(const short8*)(kbase + (size_t)(kv0n + kt2 * 16 + l4) * D_HEAD + dt * 32 + lg * 8);
#pragma unroll
      for (int n = 0; n < 4; n++)
        vf[n] = *(const short8*)(vbase + (size_t)(kv0n + vj) * D_HEAD + vd0 + n * 8);
    }

    // --- online softmax (exp2 domain). Lane: rows q=lg*4+r, col j=kt2*16+l4.
    float mt[4];
#pragma unroll
    for (int r = 0; r < 4; r++) {
      float m0 = s[0][r];
#pragma unroll
      for (int kt2 = 1; kt2 < 8; kt2++) m0 = fmaxf(m0, s[kt2][r]);
#pragma unroll
      for (int mask = 1; mask <= 8; mask <<= 1)
        m0 = fmaxf(m0, __shfl_xor(m0, mask, 64));
      mt[r] = m0;
    }
    // defer-max: skip o-rescale while running max is stable (THR=8 in log2)
    bool stable = true;
#pragma unroll
    for (int r = 0; r < 4; r++) stable &= (mt[r] <= m_[r] + 8.0f);
    if (!__all((int)stable)) {
#pragma unroll
      for (int r = 0; r < 4; r++) {
        const float mn   = fmaxf(m_[r], mt[r]);
        const float corr = exp2f(m_[r] - mn);
        l_[r] *= corr;
        o[0][r] *= corr; o[1][r] *= corr; o[2][r] *= corr; o[3][r] *= corr;
        m_[r] = mn;
      }
    }
#pragma unroll
    for (int r = 0; r < 4; r++) {
      const int qr = lg * 4 + r;
      float rs = 0.f;
#pragma unroll
      for (int kt2 = 0; kt2 < 8; kt2++) {
        const float p = exp2f(s[kt2][r] - m_[r]);
        rs += p;
        P_lds[w][qr * 136 + kt2 * 16 + l4] = f2bf(p);
      }
      l_[r] += rs;                     // per-lane partial; reduced at end
    }
    // same-wave LDS write->read: lockstep wave + drained lgkm is sufficient
    asm volatile("s_waitcnt lgkmcnt(0)" ::: "memory");
    __builtin_amdgcn_sched_barrier(0);

    // PV: O[q][d] += P(16x128) * V(128x64); contraction in 4 j-blocks of 32
    short8 pa[4];
#pragma unroll
    for (int jb = 0; jb < 4; jb++)
      pa[jb] = *(const short8*)&P_lds[w][l4 * 136 + jb * 32 + lg * 8];
    __builtin_amdgcn_s_setprio(1);
#pragma unroll
    for (int dtile = 0; dtile < 4; dtile++) {
#pragma unroll
      for (int jb = 0; jb < 4; jb++) {
        const short8 bv = *(const short8*)&Vt_lds[(dtile * 16 + l4) * 136 + jb * 32 + lg * 8];
        o[dtile] = __builtin_amdgcn_mfma_f32_16x16x32_bf16(pa[jb], bv, o[dtile], 0, 0, 0);
      }
    }
    __builtin_amdgcn_s_setprio(0);
  }

  // final: reduce per-lane l over the 16-lane column group
#pragma unroll
  for (int r = 0; r < 4; r++)
#pragma unroll
    for (int mask = 1; mask <= 8; mask <<= 1)
      l_[r] += __shfl_xor(l_[r], mask, 64);

  // epilogue: divide by l, write bf16 att[b][s][h*64+d]
  const int b_ = bh >> 3, h = bh & 7;
#pragma unroll
  for (int r = 0; r < 4; r++) {
    const int qrow = qb * 64 + w * 16 + lg * 4 + r;
    const float inv = 1.0f / l_[r];
    unsigned short* op = att + ((size_t)(b_ * SEQ + qrow)) * D_MODEL + h * D_HEAD;
#pragma unroll
    for (int dtile = 0; dtile < 4; dtile++)
      op[dtile * 16 + l4] = f2bf(o[dtile][r] * inv);
  }
}

// ---------------------------------------------------------------------------
// Kernel 4: output projection + bias + residual. grid = (ROWS/64, 8).
// ---------------------------------------------------------------------------
__global__ __launch_bounds__(256) void proj_mfma_kernel(const unsigned short* __restrict__ att,
                                                        const unsigned short* __restrict__ wot,
                                                        const float* __restrict__ bo,
                                                        const float* __restrict__ x,
                                                        float* __restrict__ out) {
  __shared__ __align__(16) unsigned short Bs[2][64 * 64];
  f32x4 acc[4];
#pragma unroll
  for (int i = 0; i < 4; i++) acc[i] = (f32x4){0.f, 0.f, 0.f, 0.f};
  bf16_gemm_lds(att, wot, Bs, acc, blockIdx.x, blockIdx.y);

  const int lane = threadIdx.x & 63, wv_ = threadIdx.x >> 6;
  const int l4 = lane & 15, lg = lane >> 4;
#pragma unroll
  for (int nt = 0; nt < 4; nt++) {
    const float bb = bo[blockIdx.y * 64 + nt * 16 + l4];
#pragma unroll
    for (int r = 0; r < 4; r++) {
      const int row = blockIdx.x * 64 + wv_ * 16 + lg * 4 + r;
      const size_t off = (size_t)row * D_MODEL + blockIdx.y * 64 + nt * 16 + l4;
      out[off] = acc[nt][r] + bb + x[off];
    }
  }
}

// ---------------------------------------------------------------------------
extern "C" void kernel_launch(void* const* d_in, const int* in_sizes, int n_in,
                              void* d_out, int out_size, void* d_ws, size_t ws_size,
                              hipStream_t stream) {
  const float* x     = (const float*)d_in[0];
  const float* wq    = (const float*)d_in[1];
  const float* bq    = (const float*)d_in[2];
  const float* wk    = (const float*)d_in[3];
  const float* bk    = (const float*)d_in[4];
  const float* wv    = (const float*)d_in[5];
  const float* bv    = (const float*)d_in[6];
  const float* wo    = (const float*)d_in[7];
  const float* bo    = (const float*)d_in[8];
  const float* gamma = (const float*)d_in[9];
  const float* beta  = (const float*)d_in[10];
  float* out = (float*)d_out;

  // bf16 workspace: xn | q | k | v (4 x 8 MiB) | wt (2 MiB); att = xn
  unsigned short* xn  = (unsigned short*)d_ws;
  unsigned short* q   = xn + (size_t)ROWS * D_MODEL;
  unsigned short* k   = q  + (size_t)ROWS * D_MODEL;
  unsigned short* v   = k  + (size_t)ROWS * D_MODEL;
  unsigned short* wt  = v  + (size_t)ROWS * D_MODEL;   // [4][512][512] n-major
  unsigned short* att = xn;  // xn dead after qkv

  wtrans_kernel<<<dim3(8, 8, 4), 256, 0, stream>>>(wq, wk, wv, wo, wt);
  ln_kernel<<<ROWS, 128, 0, stream>>>(x, gamma, beta, xn);
  qkv_mfma_kernel<<<dim3(ROWS / 64, N_HEADS, 3), 256, 0, stream>>>(
      xn, wt, bq, bk, bv, q, k, v);
  attn_mfma_kernel<<<1024, 256, 0, stream>>>(q, k, v, att);
  proj_mfma_kernel<<<dim3(ROWS / 64, D_MODEL / 64), 256, 0, stream>>>(
      att, wt + (size_t)3 * D_MODEL * D_MODEL, bo, x, out);
}